// Round 3
// baseline (285.331 us; speedup 1.0000x reference)
//
#include <hip/hip_runtime.h>
#include <hip/hip_bf16.h>

typedef __attribute__((ext_vector_type(8))) short bf16x8;
typedef __attribute__((ext_vector_type(4))) float f32x4;
typedef unsigned short u16;

__device__ __forceinline__ u16 f2bf(float f) {
  __hip_bfloat16 h = __float2bfloat16(f);  // RNE
  u16 u;
  __builtin_memcpy(&u, &h, 2);
  return u;
}
__device__ __forceinline__ bf16x8 pack8(float4 a, float4 b) {
  u16 h[8] = {f2bf(a.x), f2bf(a.y), f2bf(a.z), f2bf(a.w),
              f2bf(b.x), f2bf(b.y), f2bf(b.z), f2bf(b.w)};
  bf16x8 r;
  __builtin_memcpy(&r, h, 16);
  return r;
}

// Dims: B=64, C=512, NE=80, NI=20, E=512. fp32 I/O, bf16 MFMA compute.
// ROUND 3: fully barrier-free. Evidence: dur pinned ~100us across r0-r2
// regardless of HBM bytes (27MB warm replay = same time) -> latency-bound
// with ~2-3 loads in flight per wave, caused by per-phase __syncthreads
// vmcnt(0) drains + load->cvt->mfma chains. Fix: no LDS, no barriers;
// every wave self-sufficient; phase-A K-loop software-pipelined in regs.
//
// Grid 512 (block = column), 512 threads = 8 waves, all independent:
//   mw = wave&3 -> m-tile (16 batches); jh = wave>>2 ->
//   jh=0: e-col-tiles 0..2 ; jh=1: e-col-tiles 3..4 + i-col-tiles 0..1.
// a-frag built per-lane direct: row = m0+nidx (batch), k = kk0+quad*8..+7
// (A[m=lane&15][k=quad*8+j] layout); b-frag direct as in r2 (L1-filtered
// across the 4 m-waves; HBM sees each weight once -> FETCH ~115MB).
// C/D: C[m=quad*4+reg][n=lane&15] (m89/m91).

__global__ __launch_bounds__(512, 4) void ei_cols_mfma(
    const float* __restrict__ thal,     // [64][512]
    const float* __restrict__ inc,      // [64][512][512]
    const float* __restrict__ l23,      // [64][512][80]
    const float* __restrict__ re_in,    // [64][512][80]
    const float* __restrict__ ri_in,    // [64][512][20]
    const float* __restrict__ ev_in,    // [64][512][80]
    const float* __restrict__ iv_in,    // [64][512][20]
    const float* __restrict__ in_proj,  // [512][80][512]
    const float* __restrict__ fb_proj,  // [512][80][80]
    const float* __restrict__ w_ee,     // [512][80][80]
    const float* __restrict__ w_ei,     // [512][20][80]
    const float* __restrict__ w_ie,     // [512][80][20]
    float* __restrict__ out)            // r_e|r_i|v_e|v_i flat fp32
{
  const int c = blockIdx.x;
  const int tid = threadIdx.x;
  const int lane = tid & 63;
  const int wave = tid >> 6;
  const int nidx = lane & 15;
  const int quad = lane >> 4;
  const int mw = wave & 3;
  const int jh = wave >> 2;
  const int m0 = mw * 16;
  const int brow = m0 + nidx;  // batch row this lane's a-frag covers
  const int q8 = quad * 8;

  f32x4 acc_e[3], acc_i[2];
#pragma unroll
  for (int j = 0; j < 3; ++j) acc_e[j] = (f32x4){0.f, 0.f, 0.f, 0.f};
#pragma unroll
  for (int j = 0; j < 2; ++j) acc_i[j] = (f32x4){0.f, 0.f, 0.f, 0.f};

  const float* incR = inc + (size_t)brow * 262144 + (size_t)c * 512;
  const float* thalR = thal + (size_t)brow * 512;
  const float* wA = in_proj + (size_t)c * 40960;

  // ---- Phase A: I_ext = (thal+inc).in_proj^T, K=512 ----------------------
  // Register-pipelined: prefetch step k0+32 while MFMAing step k0.
  if (jh == 0) {
    float4 ca0 = *(const float4*)(incR + q8);
    float4 ca1 = *(const float4*)(incR + q8 + 4);
    float4 ct0 = *(const float4*)(thalR + q8);
    float4 ct1 = *(const float4*)(thalR + q8 + 4);
    float4 cw[3][2];
#pragma unroll
    for (int j = 0; j < 3; ++j) {
      const float* p = wA + (size_t)(j * 16 + nidx) * 512 + q8;
      cw[j][0] = *(const float4*)p;
      cw[j][1] = *(const float4*)(p + 4);
    }
    for (int k0 = 0; k0 < 480; k0 += 32) {
      const int kn = k0 + 32 + q8;
      float4 na0 = *(const float4*)(incR + kn);
      float4 na1 = *(const float4*)(incR + kn + 4);
      float4 nt0 = *(const float4*)(thalR + kn);
      float4 nt1 = *(const float4*)(thalR + kn + 4);
      float4 nw[3][2];
#pragma unroll
      for (int j = 0; j < 3; ++j) {
        const float* p = wA + (size_t)(j * 16 + nidx) * 512 + kn;
        nw[j][0] = *(const float4*)p;
        nw[j][1] = *(const float4*)(p + 4);
      }
      float4 s0, s1;
      s0.x = ca0.x + ct0.x; s0.y = ca0.y + ct0.y;
      s0.z = ca0.z + ct0.z; s0.w = ca0.w + ct0.w;
      s1.x = ca1.x + ct1.x; s1.y = ca1.y + ct1.y;
      s1.z = ca1.z + ct1.z; s1.w = ca1.w + ct1.w;
      bf16x8 af = pack8(s0, s1);
#pragma unroll
      for (int j = 0; j < 3; ++j) {
        bf16x8 bf = pack8(cw[j][0], cw[j][1]);
        acc_e[j] = __builtin_amdgcn_mfma_f32_16x16x32_bf16(af, bf, acc_e[j], 0, 0, 0);
      }
      ca0 = na0; ca1 = na1; ct0 = nt0; ct1 = nt1;
#pragma unroll
      for (int j = 0; j < 3; ++j) { cw[j][0] = nw[j][0]; cw[j][1] = nw[j][1]; }
    }
    {  // tail step k0 = 480
      float4 s0, s1;
      s0.x = ca0.x + ct0.x; s0.y = ca0.y + ct0.y;
      s0.z = ca0.z + ct0.z; s0.w = ca0.w + ct0.w;
      s1.x = ca1.x + ct1.x; s1.y = ca1.y + ct1.y;
      s1.z = ca1.z + ct1.z; s1.w = ca1.w + ct1.w;
      bf16x8 af = pack8(s0, s1);
#pragma unroll
      for (int j = 0; j < 3; ++j) {
        bf16x8 bf = pack8(cw[j][0], cw[j][1]);
        acc_e[j] = __builtin_amdgcn_mfma_f32_16x16x32_bf16(af, bf, acc_e[j], 0, 0, 0);
      }
    }
  } else {
    float4 ca0 = *(const float4*)(incR + q8);
    float4 ca1 = *(const float4*)(incR + q8 + 4);
    float4 ct0 = *(const float4*)(thalR + q8);
    float4 ct1 = *(const float4*)(thalR + q8 + 4);
    float4 cw[2][2];
#pragma unroll
    for (int j = 0; j < 2; ++j) {
      const float* p = wA + (size_t)((3 + j) * 16 + nidx) * 512 + q8;
      cw[j][0] = *(const float4*)p;
      cw[j][1] = *(const float4*)(p + 4);
    }
    for (int k0 = 0; k0 < 480; k0 += 32) {
      const int kn = k0 + 32 + q8;
      float4 na0 = *(const float4*)(incR + kn);
      float4 na1 = *(const float4*)(incR + kn + 4);
      float4 nt0 = *(const float4*)(thalR + kn);
      float4 nt1 = *(const float4*)(thalR + kn + 4);
      float4 nw[2][2];
#pragma unroll
      for (int j = 0; j < 2; ++j) {
        const float* p = wA + (size_t)((3 + j) * 16 + nidx) * 512 + kn;
        nw[j][0] = *(const float4*)p;
        nw[j][1] = *(const float4*)(p + 4);
      }
      float4 s0, s1;
      s0.x = ca0.x + ct0.x; s0.y = ca0.y + ct0.y;
      s0.z = ca0.z + ct0.z; s0.w = ca0.w + ct0.w;
      s1.x = ca1.x + ct1.x; s1.y = ca1.y + ct1.y;
      s1.z = ca1.z + ct1.z; s1.w = ca1.w + ct1.w;
      bf16x8 af = pack8(s0, s1);
#pragma unroll
      for (int j = 0; j < 2; ++j) {
        bf16x8 bf = pack8(cw[j][0], cw[j][1]);
        acc_e[j] = __builtin_amdgcn_mfma_f32_16x16x32_bf16(af, bf, acc_e[j], 0, 0, 0);
      }
      ca0 = na0; ca1 = na1; ct0 = nt0; ct1 = nt1;
#pragma unroll
      for (int j = 0; j < 2; ++j) { cw[j][0] = nw[j][0]; cw[j][1] = nw[j][1]; }
    }
    {  // tail
      float4 s0, s1;
      s0.x = ca0.x + ct0.x; s0.y = ca0.y + ct0.y;
      s0.z = ca0.z + ct0.z; s0.w = ca0.w + ct0.w;
      s1.x = ca1.x + ct1.x; s1.y = ca1.y + ct1.y;
      s1.z = ca1.z + ct1.z; s1.w = ca1.w + ct1.w;
      bf16x8 af = pack8(s0, s1);
#pragma unroll
      for (int j = 0; j < 2; ++j) {
        bf16x8 bf = pack8(cw[j][0], cw[j][1]);
        acc_e[j] = __builtin_amdgcn_mfma_f32_16x16x32_bf16(af, bf, acc_e[j], 0, 0, 0);
      }
    }
  }

  // ---- Phase B: I_fb = l23 . fb_proj^T, K=80 (tail-masked) ---------------
  {
    const float* l23R = l23 + ((size_t)brow * 512 + c) * 80;
    const float* fb = fb_proj + (size_t)c * 6400;
#pragma unroll
    for (int kk0 = 0; kk0 < 96; kk0 += 32) {
      const bool full = (kk0 < 64) || (quad < 2);
      float4 a0 = {0.f, 0.f, 0.f, 0.f}, a1 = {0.f, 0.f, 0.f, 0.f};
      if (full) {
        a0 = *(const float4*)(l23R + kk0 + q8);
        a1 = *(const float4*)(l23R + kk0 + q8 + 4);
      }
      bf16x8 af = pack8(a0, a1);
      if (jh == 0) {
#pragma unroll
        for (int j = 0; j < 3; ++j) {
          float4 w0 = {0.f, 0.f, 0.f, 0.f}, w1 = {0.f, 0.f, 0.f, 0.f};
          if (full) {
            const float* p = fb + (size_t)(j * 16 + nidx) * 80 + kk0 + q8;
            w0 = *(const float4*)p; w1 = *(const float4*)(p + 4);
          }
          bf16x8 bf = pack8(w0, w1);
          acc_e[j] = __builtin_amdgcn_mfma_f32_16x16x32_bf16(af, bf, acc_e[j], 0, 0, 0);
        }
      } else {
#pragma unroll
        for (int j = 0; j < 2; ++j) {
          float4 w0 = {0.f, 0.f, 0.f, 0.f}, w1 = {0.f, 0.f, 0.f, 0.f};
          if (full) {
            const float* p = fb + (size_t)((3 + j) * 16 + nidx) * 80 + kk0 + q8;
            w0 = *(const float4*)p; w1 = *(const float4*)(p + 4);
          }
          bf16x8 bf = pack8(w0, w1);
          acc_e[j] = __builtin_amdgcn_mfma_f32_16x16x32_bf16(af, bf, acc_e[j], 0, 0, 0);
        }
      }
    }
  }

  // ---- Phase C: I_ee = r_e.W_ee^T ; I_ei = r_e.W_ei^T --------------------
  {
    const float* reR = re_in + ((size_t)brow * 512 + c) * 80;
    const float* wee = w_ee + (size_t)c * 6400;
    const float* wei = w_ei + (size_t)c * 1600;
#pragma unroll
    for (int kk0 = 0; kk0 < 96; kk0 += 32) {
      const bool full = (kk0 < 64) || (quad < 2);
      float4 a0 = {0.f, 0.f, 0.f, 0.f}, a1 = {0.f, 0.f, 0.f, 0.f};
      if (full) {
        a0 = *(const float4*)(reR + kk0 + q8);
        a1 = *(const float4*)(reR + kk0 + q8 + 4);
      }
      bf16x8 af = pack8(a0, a1);
      if (jh == 0) {
#pragma unroll
        for (int j = 0; j < 3; ++j) {
          float4 w0 = {0.f, 0.f, 0.f, 0.f}, w1 = {0.f, 0.f, 0.f, 0.f};
          if (full) {
            const float* p = wee + (size_t)(j * 16 + nidx) * 80 + kk0 + q8;
            w0 = *(const float4*)p; w1 = *(const float4*)(p + 4);
          }
          bf16x8 bf = pack8(w0, w1);
          acc_e[j] = __builtin_amdgcn_mfma_f32_16x16x32_bf16(af, bf, acc_e[j], 0, 0, 0);
        }
      } else {
#pragma unroll
        for (int j = 0; j < 2; ++j) {
          float4 w0 = {0.f, 0.f, 0.f, 0.f}, w1 = {0.f, 0.f, 0.f, 0.f};
          if (full) {
            const float* p = wee + (size_t)((3 + j) * 16 + nidx) * 80 + kk0 + q8;
            w0 = *(const float4*)p; w1 = *(const float4*)(p + 4);
          }
          bf16x8 bf = pack8(w0, w1);
          acc_e[j] = __builtin_amdgcn_mfma_f32_16x16x32_bf16(af, bf, acc_e[j], 0, 0, 0);
        }
#pragma unroll
        for (int j = 0; j < 2; ++j) {
          const int row = j * 16 + nidx;
          float4 w0 = {0.f, 0.f, 0.f, 0.f}, w1 = {0.f, 0.f, 0.f, 0.f};
          if (row < 20 && full) {
            const float* p = wei + (size_t)row * 80 + kk0 + q8;
            w0 = *(const float4*)p; w1 = *(const float4*)(p + 4);
          }
          bf16x8 bf = pack8(w0, w1);
          acc_i[j] = __builtin_amdgcn_mfma_f32_16x16x32_bf16(af, bf, acc_i[j], 0, 0, 0);
        }
      }
    }
  }

  // ---- Phase D: I_ie = r_i . (-W_ie)^T, K=20 (pad to 32) -----------------
  {
    const float* riR = ri_in + ((size_t)brow * 512 + c) * 20;
    float4 a0 = {0.f, 0.f, 0.f, 0.f}, a1 = {0.f, 0.f, 0.f, 0.f};
    if (quad <= 2) a0 = *(const float4*)(riR + q8);        // k=q8..q8+3 (<20)
    if (quad <= 1) a1 = *(const float4*)(riR + q8 + 4);    // k=q8+4..q8+7
    bf16x8 af = pack8(a0, a1);
    auto wieF = [&](int row) -> bf16x8 {
      const float* p = w_ie + (size_t)c * 1600 + row * 20 + q8;
      float4 w0 = {0.f, 0.f, 0.f, 0.f}, w1 = {0.f, 0.f, 0.f, 0.f};
      if (quad < 2) { w0 = *(const float4*)p; w1 = *(const float4*)(p + 4); }
      else if (quad == 2) { w0 = *(const float4*)p; }
      w0.x = -w0.x; w0.y = -w0.y; w0.z = -w0.z; w0.w = -w0.w;
      w1.x = -w1.x; w1.y = -w1.y; w1.z = -w1.z; w1.w = -w1.w;
      return pack8(w0, w1);
    };
    if (jh == 0) {
#pragma unroll
      for (int j = 0; j < 3; ++j) {
        bf16x8 bf = wieF(j * 16 + nidx);
        acc_e[j] = __builtin_amdgcn_mfma_f32_16x16x32_bf16(af, bf, acc_e[j], 0, 0, 0);
      }
    } else {
#pragma unroll
      for (int j = 0; j < 2; ++j) {
        bf16x8 bf = wieF((3 + j) * 16 + nidx);
        acc_e[j] = __builtin_amdgcn_mfma_f32_16x16x32_bf16(af, bf, acc_e[j], 0, 0, 0);
      }
    }
  }

  // ---- Epilogue: v = v_old + 0.1*(I - v_old) ; r = relu(v), direct -------
  // C/D mapping: row = m0+quad*4+r, col = tile*16+nidx.
  {
    const size_t R_ri = 2621440u;
    const size_t R_ve = 3276800u;
    const size_t R_vi = 5898240u;
    const int row0 = m0 + quad * 4;
    if (jh == 0) {
#pragma unroll
      for (int j = 0; j < 3; ++j) {
        const int col = j * 16 + nidx;
#pragma unroll
        for (int r = 0; r < 4; ++r) {
          size_t g = ((size_t)(row0 + r) * 512 + c) * 80 + col;
          float e0 = ev_in[g];
          float v = e0 + 0.1f * (acc_e[j][r] - e0);
          out[g] = fmaxf(v, 0.f);
          out[R_ve + g] = v;
        }
      }
    } else {
#pragma unroll
      for (int j = 0; j < 2; ++j) {
        const int col = 48 + j * 16 + nidx;
#pragma unroll
        for (int r = 0; r < 4; ++r) {
          size_t g = ((size_t)(row0 + r) * 512 + c) * 80 + col;
          float e0 = ev_in[g];
          float v = e0 + 0.1f * (acc_e[j][r] - e0);
          out[g] = fmaxf(v, 0.f);
          out[R_ve + g] = v;
        }
      }
#pragma unroll
      for (int j = 0; j < 2; ++j) {
        const int col = j * 16 + nidx;
        if (col < 20) {
#pragma unroll
          for (int r = 0; r < 4; ++r) {
            size_t g = ((size_t)(row0 + r) * 512 + c) * 20 + col;
            float i0 = iv_in[g];
            float v = i0 + 0.1f * (acc_i[j][r] - i0);
            out[R_ri + g] = fmaxf(v, 0.f);
            out[R_vi + g] = v;
          }
        }
      }
    }
  }
}

extern "C" void kernel_launch(void* const* d_in, const int* in_sizes, int n_in,
                              void* d_out, int out_size, void* d_ws, size_t ws_size,
                              hipStream_t stream) {
  const float* thal = (const float*)d_in[0];
  const float* inc = (const float*)d_in[1];
  const float* l23 = (const float*)d_in[2];
  const float* re = (const float*)d_in[3];
  const float* ri = (const float*)d_in[4];
  const float* ev = (const float*)d_in[5];
  const float* iv = (const float*)d_in[6];
  const float* in_proj = (const float*)d_in[7];
  const float* fb_proj = (const float*)d_in[8];
  const float* w_ee = (const float*)d_in[9];
  const float* w_ei = (const float*)d_in[10];
  const float* w_ie = (const float*)d_in[11];
  float* out = (float*)d_out;
  ei_cols_mfma<<<dim3(512), dim3(512), 0, stream>>>(
      thal, inc, l23, re, ri, ev, iv, in_proj, fb_proj, w_ee, w_ei, w_ie, out);
}

// Round 4
// 256.777 us; speedup vs baseline: 1.1112x; 1.1112x over previous
//
#include <hip/hip_runtime.h>
#include <hip/hip_bf16.h>

typedef __attribute__((ext_vector_type(8))) short bf16x8;
typedef __attribute__((ext_vector_type(4))) float f32x4;
typedef unsigned short u16;

__device__ __forceinline__ u16 f2bf(float f) {
  __hip_bfloat16 h = __float2bfloat16(f);  // RNE
  u16 u;
  __builtin_memcpy(&u, &h, 2);
  return u;
}
__device__ __forceinline__ bf16x8 packv(f32x4 a, f32x4 b) {
  u16 h[8] = {f2bf(a[0]), f2bf(a[1]), f2bf(a[2]), f2bf(a[3]),
              f2bf(b[0]), f2bf(b[1]), f2bf(b[2]), f2bf(b[3])};
  bf16x8 r;
  __builtin_memcpy(&r, h, 16);
  return r;
}

// DMA global->LDS, 16B per lane, linear dest (base + lane*16).
__device__ __forceinline__ void g2l(const float* g, char* l) {
  __builtin_amdgcn_global_load_lds(
      (const __attribute__((address_space(1))) void*)g,
      (__attribute__((address_space(3))) void*)l, 16, 0, 0);
}
template <int N>
__device__ __forceinline__ void waitvm() {
  asm volatile("s_waitcnt vmcnt(%0)" ::"i"(N) : "memory");
  __builtin_amdgcn_sched_barrier(0);
}
#define MFENCE() asm volatile("" ::: "memory")

// Dims: B=64, C=512, NE=80, NI=20, E=512. fp32 I/O, bf16 MFMA compute.
// ROUND 4: single 15-step DMA pipeline (T3/T4 counted-vmcnt template).
// Evidence r0-r3: delivered BW pinned 1.4-2.0 TB/s; lookahead depth ~1
// (syncthreads vmcnt(0) drains or regalloc-collapsed prefetch). Fix:
// global_load_lds (VGPR-free queue) + vmcnt(N) never 0 + raw s_barrier.
// Steps: s0-7 A(I_ext,K=64 each), s8-10 B(I_fb,K=32/32/16),
//        s11-13 C(I_ee+I_ei,K=32/32/16), s14 D(I_ie,K=20).
// Ping-pong buf[2] x 36KB. Per-wave DMA counts/step: A=9,B32=5,B16=3,
// C32=6,C16=3,D=3. At step s: bar; issue DMA(s+1); vmcnt(N_{s+1}); bar;
// compute s. fp32 in LDS; cvt at frag read. XOR-swizzle via pre-swizzled
// GLOBAL source + swizzled read (linear DMA dest), rows 256B/128B/64B.
// Block 256 thr = 4 waves (wave = m-tile of 16 batches, all 7 col-tiles).
// LDS 73728 -> 2 blocks/CU (8 waves). thal reg-prefetched 1 step ahead,
// issued BEFORE next DMA batch so vmcnt(N) forces it (no extra drain).

__global__ __launch_bounds__(256, 2) void ei_cols_mfma(
    const float* __restrict__ thal,     // [64][512]
    const float* __restrict__ inc,      // [64][512][512]
    const float* __restrict__ l23,      // [64][512][80]
    const float* __restrict__ re_in,    // [64][512][80]
    const float* __restrict__ ri_in,    // [64][512][20]
    const float* __restrict__ ev_in,    // [64][512][80]
    const float* __restrict__ iv_in,    // [64][512][20]
    const float* __restrict__ in_proj,  // [512][80][512]
    const float* __restrict__ fb_proj,  // [512][80][80]
    const float* __restrict__ w_ee,     // [512][80][80]
    const float* __restrict__ w_ei,     // [512][20][80]
    const float* __restrict__ w_ie,     // [512][80][20]
    float* __restrict__ out)            // r_e|r_i|v_e|v_i flat fp32
{
  constexpr int BUF = 36864;
  __shared__ __align__(16) char smem[2 * BUF];
  const int c = blockIdx.x;
  const int tid = threadIdx.x;
  const int lane = tid & 63;
  const int wave = tid >> 6;
  const int nidx = lane & 15;
  const int quad = lane >> 4;
  const int m0 = wave * 16;
  const int brow = m0 + nidx;
  const int q8 = quad * 8;

  f32x4 acc_e[5], acc_i[2];
#pragma unroll
  for (int j = 0; j < 5; ++j) acc_e[j] = (f32x4){0.f, 0.f, 0.f, 0.f};
#pragma unroll
  for (int j = 0; j < 2; ++j) acc_i[j] = (f32x4){0.f, 0.f, 0.f, 0.f};

  auto bar = [&] { MFENCE(); __builtin_amdgcn_s_barrier(); MFENCE(); };

  // ---------------- DMA issue (per-wave fixed counts) ----------------------
  // A-step buf: inc fp32 [64][64] @0 (16KB), W fp32 [80][64] @16KB (20KB).
  auto issueA = [&](int k0, int p) {
    char* B = smem + p * BUF;
#pragma unroll
    for (int t = 0; t < 9; ++t) {
      const int idx = wave * 9 + t;
      const float* g;
      if (idx < 16) {
        const int L = idx * 64 + lane;
        const int row = L >> 4, ch = (L & 15) ^ (row & 15);
        g = inc + ((size_t)row * 512 + c) * 512 + k0 + (ch << 2);
      } else {
        const int L = (idx - 16) * 64 + lane;
        const int row = L >> 4, ch = (L & 15) ^ (row & 15);
        g = in_proj + (size_t)c * 40960 + (size_t)row * 512 + k0 + (ch << 2);
      }
      g2l(g, B + idx * 1024);
    }
  };
  // K32 buf: a [64][32] @0 (8KB), b [80][32] @8KB (10KB), i [20+][32] @18KB.
  auto issue32 = [&](const float* aP, const float* bP, const float* iP,
                     bool hasI, int kg, int p) {
    char* B = smem + p * BUF;
    const int n = hasI ? 6 : 5;
    for (int t = 0; t < n; ++t) {
      const int idx = wave * n + t;
      const float* g;
      if (idx < 8) {
        const int L = idx * 64 + lane;
        const int row = L >> 3, ch = (L & 7) ^ (row & 7);
        g = aP + ((size_t)row * 512 + c) * 80 + kg + (ch << 2);
      } else if (idx < 18) {
        const int L = (idx - 8) * 64 + lane;
        const int row = L >> 3, ch = (L & 7) ^ (row & 7);
        g = bP + ((size_t)c * 80 + row) * 80 + kg + (ch << 2);
      } else if (hasI && idx < 21) {
        const int L = (idx - 18) * 64 + lane;
        const int Lc = L < 160 ? L : 159;
        const int row = Lc >> 3, ch = (Lc & 7) ^ (row & 7);
        g = iP + ((size_t)c * 20 + row) * 80 + kg + (ch << 2);
      } else {
        g = thal + (lane << 2);  // pad (keeps per-wave count uniform)
      }
      g2l(g, B + idx * 1024);
    }
  };
  // K16 buf (k=64..79): a [64][16] @0, b [80][16] @4KB, i [20+][16] @9KB.
  auto issue16 = [&](const float* aP, const float* bP, const float* iP,
                     bool hasI, int p) {
    char* B = smem + p * BUF;
#pragma unroll
    for (int t = 0; t < 3; ++t) {
      const int idx = wave * 3 + t;
      const float* g;
      if (idx < 4) {
        const int L = idx * 64 + lane;
        const int row = L >> 2, ch = (L & 3) ^ (row & 3);
        g = aP + ((size_t)row * 512 + c) * 80 + 64 + (ch << 2);
      } else if (idx < 9) {
        const int L = (idx - 4) * 64 + lane;
        const int row = L >> 2, ch = (L & 3) ^ (row & 3);
        g = bP + ((size_t)c * 80 + row) * 80 + 64 + (ch << 2);
      } else if (hasI && idx < 11) {
        const int L = (idx - 9) * 64 + lane;
        const int Lc = L < 80 ? L : 79;
        const int row = Lc >> 2, ch = (Lc & 3) ^ (row & 3);
        g = iP + ((size_t)c * 20 + row) * 80 + 64 + (ch << 2);
      } else {
        g = thal + (lane << 2);
      }
      g2l(g, B + idx * 1024);
    }
  };
  // D buf: ri [64][20] @0 (5KB), wie [80][20] @5KB (rows 80B, no swizzle).
  auto issueD = [&](int p) {
    char* B = smem + p * BUF;
#pragma unroll
    for (int t = 0; t < 3; ++t) {
      const int idx = wave * 3 + t;
      const float* g;
      if (idx < 5) {
        const int L = idx * 64 + lane;
        const int row = L / 5, ch = L % 5;
        g = ri_in + ((size_t)row * 512 + c) * 20 + (ch << 2);
      } else {
        const int L = (idx - 5) * 64 + lane;
        const int Lc = L < 400 ? L : 399;
        const int row = Lc / 5, ch = Lc % 5;
        g = w_ie + ((size_t)c * 80 + row) * 20 + (ch << 2);
      }
      g2l(g, B + idx * 1024);
    }
  };

  // ---------------- compute (frag read fp32 LDS + cvt + MFMA) --------------
  auto computeA = [&](int p, const f32x4* tc) {
    const float* As = (const float*)(smem + p * BUF);
    const float* Ws = As + 4096;
    const int rA = m0 + nidx;
#pragma unroll
    for (int h = 0; h < 2; ++h) {
      const int c0 = h * 8 + quad * 2;
      f32x4 a0 = *(const f32x4*)(As + rA * 64 + (((c0) ^ nidx) << 2));
      f32x4 a1 = *(const f32x4*)(As + rA * 64 + (((c0 + 1) ^ nidx) << 2));
      a0 += tc[2 * h];
      a1 += tc[2 * h + 1];
      bf16x8 af = packv(a0, a1);
#pragma unroll
      for (int j = 0; j < 5; ++j) {
        const int rB = j * 16 + nidx;
        f32x4 b0 = *(const f32x4*)(Ws + rB * 64 + (((c0) ^ nidx) << 2));
        f32x4 b1 = *(const f32x4*)(Ws + rB * 64 + (((c0 + 1) ^ nidx) << 2));
        acc_e[j] = __builtin_amdgcn_mfma_f32_16x16x32_bf16(af, packv(b0, b1),
                                                           acc_e[j], 0, 0, 0);
      }
    }
  };
  auto compute32 = [&](int p, bool doI) {
    const float* As = (const float*)(smem + p * BUF);
    const float* Bs = As + 2048;
    const float* Is = As + 4608;
    const int s7 = nidx & 7;
    const int c0 = quad * 2;
    const int rA = m0 + nidx;
    f32x4 a0 = *(const f32x4*)(As + rA * 32 + ((c0 ^ s7) << 2));
    f32x4 a1 = *(const f32x4*)(As + rA * 32 + (((c0 + 1) ^ s7) << 2));
    bf16x8 af = packv(a0, a1);
#pragma unroll
    for (int j = 0; j < 5; ++j) {
      const int rB = j * 16 + nidx;
      f32x4 b0 = *(const f32x4*)(Bs + rB * 32 + ((c0 ^ s7) << 2));
      f32x4 b1 = *(const f32x4*)(Bs + rB * 32 + (((c0 + 1) ^ s7) << 2));
      acc_e[j] = __builtin_amdgcn_mfma_f32_16x16x32_bf16(af, packv(b0, b1),
                                                         acc_e[j], 0, 0, 0);
    }
    if (doI) {
      f32x4 b0 = *(const f32x4*)(Is + nidx * 32 + ((c0 ^ s7) << 2));
      f32x4 b1 = *(const f32x4*)(Is + nidx * 32 + (((c0 + 1) ^ s7) << 2));
      acc_i[0] = __builtin_amdgcn_mfma_f32_16x16x32_bf16(af, packv(b0, b1),
                                                         acc_i[0], 0, 0, 0);
      f32x4 z = {0.f, 0.f, 0.f, 0.f};
      f32x4 d0 = z, d1 = z;
      if (nidx < 4) {
        const int r6 = 16 + nidx;
        d0 = *(const f32x4*)(Is + r6 * 32 + ((c0 ^ s7) << 2));
        d1 = *(const f32x4*)(Is + r6 * 32 + (((c0 + 1) ^ s7) << 2));
      }
      acc_i[1] = __builtin_amdgcn_mfma_f32_16x16x32_bf16(af, packv(d0, d1),
                                                         acc_i[1], 0, 0, 0);
    }
  };
  auto compute16 = [&](int p, bool doI) {
    const float* As = (const float*)(smem + p * BUF);
    const float* Bs = As + 1024;
    const float* Is = As + 2304;
    const int s3 = nidx & 3;
    const bool act = quad < 2;
    const int c0 = quad * 2;
    const int rA = m0 + nidx;
    f32x4 z = {0.f, 0.f, 0.f, 0.f};
    f32x4 a0 = z, a1 = z;
    if (act) {
      a0 = *(const f32x4*)(As + rA * 16 + ((c0 ^ s3) << 2));
      a1 = *(const f32x4*)(As + rA * 16 + (((c0 + 1) ^ s3) << 2));
    }
    bf16x8 af = packv(a0, a1);
#pragma unroll
    for (int j = 0; j < 5; ++j) {
      const int rB = j * 16 + nidx;
      f32x4 b0 = z, b1 = z;
      if (act) {
        b0 = *(const f32x4*)(Bs + rB * 16 + ((c0 ^ s3) << 2));
        b1 = *(const f32x4*)(Bs + rB * 16 + (((c0 + 1) ^ s3) << 2));
      }
      acc_e[j] = __builtin_amdgcn_mfma_f32_16x16x32_bf16(af, packv(b0, b1),
                                                         acc_e[j], 0, 0, 0);
    }
    if (doI) {
      f32x4 b0 = z, b1 = z;
      if (act) {
        b0 = *(const f32x4*)(Is + nidx * 16 + ((c0 ^ s3) << 2));
        b1 = *(const f32x4*)(Is + nidx * 16 + (((c0 + 1) ^ s3) << 2));
      }
      acc_i[0] = __builtin_amdgcn_mfma_f32_16x16x32_bf16(af, packv(b0, b1),
                                                         acc_i[0], 0, 0, 0);
      f32x4 d0 = z, d1 = z;
      if (act && nidx < 4) {
        const int r6 = 16 + nidx;
        d0 = *(const f32x4*)(Is + r6 * 16 + ((c0 ^ s3) << 2));
        d1 = *(const f32x4*)(Is + r6 * 16 + (((c0 + 1) ^ s3) << 2));
      }
      acc_i[1] = __builtin_amdgcn_mfma_f32_16x16x32_bf16(af, packv(d0, d1),
                                                         acc_i[1], 0, 0, 0);
    }
  };
  auto computeD = [&](int p) {
    const float* Ri = (const float*)(smem + p * BUF);
    const float* Wn = Ri + 1280;
    const int rA = m0 + nidx;
    f32x4 z = {0.f, 0.f, 0.f, 0.f};
    f32x4 a0 = z, a1 = z;
    if (quad < 2) {
      a0 = *(const f32x4*)(Ri + rA * 20 + q8);
      a1 = *(const f32x4*)(Ri + rA * 20 + q8 + 4);
    } else if (quad == 2) {
      a0 = *(const f32x4*)(Ri + rA * 20 + 16);
    }
    bf16x8 af = packv(a0, a1);
#pragma unroll
    for (int j = 0; j < 5; ++j) {
      const int rB = j * 16 + nidx;
      f32x4 b0 = z, b1 = z;
      if (quad < 2) {
        b0 = *(const f32x4*)(Wn + rB * 20 + q8);
        b1 = *(const f32x4*)(Wn + rB * 20 + q8 + 4);
      } else if (quad == 2) {
        b0 = *(const f32x4*)(Wn + rB * 20 + 16);
      }
      acc_e[j] = __builtin_amdgcn_mfma_f32_16x16x32_bf16(af, packv(-b0, -b1),
                                                         acc_e[j], 0, 0, 0);
    }
  };

  // thal register prefetch (L2-hot; issued BEFORE next DMA batch so counted
  // vmcnt forces completion without draining the DMA queue).
  f32x4 tc[4], tn[4];
  auto ldThal = [&](f32x4* t, int k0) {
    const float* tb = thal + (size_t)brow * 512 + k0 + q8;
    t[0] = *(const f32x4*)(tb);
    t[1] = *(const f32x4*)(tb + 4);
    t[2] = *(const f32x4*)(tb + 32);
    t[3] = *(const f32x4*)(tb + 36);
  };

  float evr[5][4], ivr[2][4];
  auto loadEV = [&] {
    const int r0w = m0 + quad * 4;
#pragma unroll
    for (int j = 0; j < 5; ++j) {
      const int col = j * 16 + nidx;
#pragma unroll
      for (int r = 0; r < 4; ++r)
        evr[j][r] = ev_in[((size_t)(r0w + r) * 512 + c) * 80 + col];
    }
#pragma unroll
    for (int r = 0; r < 4; ++r) {
      ivr[0][r] = iv_in[((size_t)(r0w + r) * 512 + c) * 20 + nidx];
      ivr[1][r] = 0.f;
    }
    if (nidx < 4) {
#pragma unroll
      for (int r = 0; r < 4; ++r)
        ivr[1][r] = iv_in[((size_t)(r0w + r) * 512 + c) * 20 + 16 + nidx];
    }
  };

  // ---------------- the 15-step pipeline -----------------------------------
  ldThal(tc, 0);
  issueA(0, 0);
#pragma unroll
  for (int s = 0; s < 8; ++s) {
    bar();
    if (s < 7)
      issueA((s + 1) * 64, (s + 1) & 1);
    else
      issue32(l23, fb_proj, nullptr, false, 0, 0);  // step 8 -> buf0
    if (s < 7)
      waitvm<9>();
    else
      waitvm<5>();
    bar();
    if (s < 7) ldThal(tn, (s + 1) * 64);
    computeA(s & 1, tc);
#pragma unroll
    for (int u = 0; u < 4; ++u) tc[u] = tn[u];
  }
  // s8: B k0..31 (buf0); prefetch s9
  bar();
  issue32(l23, fb_proj, nullptr, false, 32, 1);
  waitvm<5>();
  bar();
  compute32(0, false);
  // s9: B k32..63 (buf1); prefetch s10
  bar();
  issue16(l23, fb_proj, nullptr, false, 0);
  waitvm<3>();
  bar();
  compute32(1, false);
  // s10: B k64..79 (buf0); prefetch s11
  bar();
  issue32(re_in, w_ee, w_ei, true, 0, 1);
  waitvm<6>();
  bar();
  compute16(0, false);
  // s11: C k0..31 (buf1); prefetch s12
  bar();
  issue32(re_in, w_ee, w_ei, true, 32, 0);
  waitvm<6>();
  bar();
  compute32(1, true);
  // s12: C k32..63 (buf0); prefetch s13; ev/iv prefetch rides the queue
  bar();
  issue16(re_in, w_ee, w_ei, true, 1);
  waitvm<3>();
  bar();
  loadEV();
  compute32(0, true);
  // s13: C k64..79 (buf1); prefetch s14
  bar();
  issueD(0);
  waitvm<3>();
  bar();
  compute16(1, true);
  // s14: D (buf0)
  bar();
  waitvm<0>();
  bar();
  computeD(0);

  // ---- Epilogue: v = v_old + 0.1*(I - v_old) ; r = relu(v) ---------------
  {
    const size_t R_ri = 2621440u;
    const size_t R_ve = 3276800u;
    const size_t R_vi = 5898240u;
    const int r0w = m0 + quad * 4;
#pragma unroll
    for (int j = 0; j < 5; ++j) {
      const int col = j * 16 + nidx;
#pragma unroll
      for (int r = 0; r < 4; ++r) {
        size_t g = ((size_t)(r0w + r) * 512 + c) * 80 + col;
        float e0 = evr[j][r];
        float v = e0 + 0.1f * (acc_e[j][r] - e0);
        out[g] = fmaxf(v, 0.f);
        out[R_ve + g] = v;
      }
    }
#pragma unroll
    for (int jj = 0; jj < 2; ++jj) {
      const int col = jj * 16 + nidx;
      if (col < 20) {
#pragma unroll
        for (int r = 0; r < 4; ++r) {
          size_t g = ((size_t)(r0w + r) * 512 + c) * 20 + col;
          float i0 = ivr[jj][r];
          float v = i0 + 0.1f * (acc_i[jj][r] - i0);
          out[R_ri + g] = fmaxf(v, 0.f);
          out[R_vi + g] = v;
        }
      }
    }
  }
}

extern "C" void kernel_launch(void* const* d_in, const int* in_sizes, int n_in,
                              void* d_out, int out_size, void* d_ws, size_t ws_size,
                              hipStream_t stream) {
  const float* thal = (const float*)d_in[0];
  const float* inc = (const float*)d_in[1];
  const float* l23 = (const float*)d_in[2];
  const float* re = (const float*)d_in[3];
  const float* ri = (const float*)d_in[4];
  const float* ev = (const float*)d_in[5];
  const float* iv = (const float*)d_in[6];
  const float* in_proj = (const float*)d_in[7];
  const float* fb_proj = (const float*)d_in[8];
  const float* w_ee = (const float*)d_in[9];
  const float* w_ei = (const float*)d_in[10];
  const float* w_ie = (const float*)d_in[11];
  float* out = (float*)d_out;
  ei_cols_mfma<<<dim3(512), dim3(256), 0, stream>>>(
      thal, inc, l23, re, ri, ev, iv, in_proj, fb_proj, w_ee, w_ei, w_ie, out);
}